// Round 11
// baseline (13931.400 us; speedup 1.0000x reference)
//
#include <hip/hip_runtime.h>

#define H 22
#define HH 484
#define EPS 1e-5f
#define SLOPE 0.01f
#define NT 256
#define NBLK 512
#define WPB 4
#define NWAVES (NBLK * WPB)  // 2048 waves
#define TPW 32               // 65536 tiles / 2048 waves

typedef __attribute__((ext_vector_type(8))) _Float16 half8;
typedef __attribute__((ext_vector_type(4))) float f32x4;

#define MFMA(A, B, C) __builtin_amdgcn_mfma_f32_16x16x32_f16(A, B, C, 0, 0, 0)

__device__ __forceinline__ float leakyf(float u) { return u > 0.f ? u : SLOPE * u; }

// k/m map used consistently for all operands; C-frag m == B-elem k per lane,
// so chained matmuls repack in-lane (see round-8 derivation).
__device__ __forceinline__ int kmap(int g, int e) {
  return ((e >> 2) << 4) + (g << 2) + (e & 3);
}

__device__ __forceinline__ half8 buildA(const float* __restrict__ W, int rows, int cols,
                                        int mbase, int kbase, int g) {
  int m = mbase + ((int)threadIdx.x & 15);
  half8 a;
#pragma unroll
  for (int e = 0; e < 8; e++) {
    int k = kbase + kmap(g, e);
    float v = (m < rows && k < cols) ? W[m * cols + k] : 0.f;
    a[e] = (_Float16)v;
  }
  return a;
}

__device__ __forceinline__ float accload(const float* p) {
  return __hip_atomic_load(p, __ATOMIC_ACQUIRE, __HIP_MEMORY_SCOPE_AGENT);
}

// raw per-lane gather of a 22-vector at features m=kmap(g,e)
__device__ __forceinline__ void raw8(const float* __restrict__ p, int g, float* v) {
#pragma unroll
  for (int e = 0; e < 8; e++) { int m = kmap(g, e); v[e] = (m < H) ? p[m] : 0.f; }
}

// BN coeffs (folded bias): a = g*rsqrt(var+eps), bf = a*b + be - a*mu
__device__ __forceinline__ void coeffs8(const float* __restrict__ acc,
                                        const float* __restrict__ gg,
                                        const float* __restrict__ be,
                                        const float* __restrict__ b,
                                        float invN, int g, float* av, float* bfv) {
#pragma unroll
  for (int e = 0; e < 8; e++) {
    int m = kmap(g, e);
    float a = 0.f, bf = 0.f;
    if (m < H) {
      float su = accload(acc + m), sq = accload(acc + H + m);
      float mu = su * invN;
      float var = sq * invN - mu * mu;
      a = gg[m] * rsqrtf(var + EPS);
      bf = a * b[m] + be[m] - a * mu;
    }
    av[e] = a; bfv[e] = bf;
  }
}

__device__ __forceinline__ void commit_stats(float* s, float* q,
                                             float red[WPB][2 * H],
                                             float* __restrict__ accOut) {
  int lane = (int)threadIdx.x & 63, w = (int)threadIdx.x >> 6, g = lane >> 4;
#pragma unroll
  for (int r = 0; r < 8; r++) {
#pragma unroll
    for (int off = 1; off < 16; off <<= 1) {
      s[r] += __shfl_xor(s[r], off);
      q[r] += __shfl_xor(q[r], off);
    }
  }
  if ((lane & 15) == 0) {
#pragma unroll
    for (int r = 0; r < 8; r++) {
      int m = kmap(g, r);
      if (m < H) { red[w][m] = s[r]; red[w][H + m] = q[r]; }
    }
  }
  __syncthreads();
  if ((int)threadIdx.x < 2 * H) {
    float v = red[0][threadIdx.x] + red[1][threadIdx.x] +
              red[2][threadIdx.x] + red[3][threadIdx.x];
    atomicAdd(&accOut[threadIdx.x], v);
  }
  __syncthreads();
}

// device-wide barrier; all NBLK blocks co-resident by __launch_bounds__(NT,2) arithmetic
__device__ __forceinline__ void gridbar(int* bar) {
  __syncthreads();
  if (threadIdx.x == 0) {
    __hip_atomic_fetch_add(bar, 1, __ATOMIC_ACQ_REL, __HIP_MEMORY_SCOPE_AGENT);
    while (__hip_atomic_load(bar, __ATOMIC_ACQUIRE, __HIP_MEMORY_SCOPE_AGENT) < NBLK)
      __builtin_amdgcn_s_sleep(2);
  }
  __syncthreads();
}

__global__ void __launch_bounds__(NT, 2) fused_kernel(
    const float* __restrict__ x, const float* __restrict__ Wp,
    const float* __restrict__ bp, const float* __restrict__ g0,
    const float* __restrict__ be0,
    const float* __restrict__ W1s, const float* __restrict__ b1s,
    const float* __restrict__ g1s, const float* __restrict__ be1s,
    const float* __restrict__ W2s, const float* __restrict__ b2s,
    const float* __restrict__ g2s, const float* __restrict__ be2s,
    const float* __restrict__ Wo, const float* __restrict__ bo,
    half8* __restrict__ bufT, float* __restrict__ acc,
    int* __restrict__ bars, float* __restrict__ out, float invN) {
  __shared__ float red[WPB][2 * H];
  int tid = threadIdx.x;
  int lane = tid & 63, w = tid >> 6, g = lane >> 4, n = lane & 15;
  int wid = blockIdx.x * WPB + w;
  int tbase = wid * TPW;
  size_t fb = (size_t)tbase * 64 + g * 16 + n;  // this lane's half8 slot in tile tbase

  float s[8], q[8];

  // ================= Phase 0: proj  z0 = Wp@x + bp =================
  {
    half8 A00 = buildA(Wp, H, 64, 0, 0, g);
    half8 A01 = buildA(Wp, H, 64, 0, 32, g);
    half8 A10 = buildA(Wp, H, 64, 16, 0, g);
    half8 A11 = buildA(Wp, H, 64, 16, 32, g);
    float bpv[8]; raw8(bp, g, bpv);
#pragma unroll
    for (int e = 0; e < 8; e++) { s[e] = 0.f; q[e] = 0.f; }
    const float4* x4 = (const float4*)x;
#pragma unroll 1
    for (int i = 0; i < TPW; i++) {
      size_t row = (size_t)(tbase + i) * 16 + n;
      float4 L0 = x4[row * 16 + g];
      float4 L1 = x4[row * 16 + 4 + g];
      float4 L2 = x4[row * 16 + 8 + g];
      float4 L3 = x4[row * 16 + 12 + g];
      half8 B0, B1;
      B0[0] = (_Float16)L0.x; B0[1] = (_Float16)L0.y; B0[2] = (_Float16)L0.z; B0[3] = (_Float16)L0.w;
      B0[4] = (_Float16)L1.x; B0[5] = (_Float16)L1.y; B0[6] = (_Float16)L1.z; B0[7] = (_Float16)L1.w;
      B1[0] = (_Float16)L2.x; B1[1] = (_Float16)L2.y; B1[2] = (_Float16)L2.z; B1[3] = (_Float16)L2.w;
      B1[4] = (_Float16)L3.x; B1[5] = (_Float16)L3.y; B1[6] = (_Float16)L3.z; B1[7] = (_Float16)L3.w;
      f32x4 c0 = {0.f, 0.f, 0.f, 0.f}, c1 = {0.f, 0.f, 0.f, 0.f};
      c0 = MFMA(A00, B0, c0); c0 = MFMA(A01, B1, c0);
      c1 = MFMA(A10, B0, c1); c1 = MFMA(A11, B1, c1);
      half8 zb;
#pragma unroll
      for (int e = 0; e < 8; e++) {
        float z = ((e < 4) ? c0[e & 3] : c1[e & 3]) + bpv[e];
        s[e] += z; q[e] += z * z;
        zb[e] = (_Float16)z;
      }
      bufT[fb + (size_t)i * 64] = zb;
    }
    commit_stats(s, q, red, acc + 0);
  }
  gridbar(bars + 0);

  // ================= Phase 1: bn0 in place + stats z1_0 =================
  {
    float aK[8], cK[8], b1v[8];
#pragma unroll
    for (int e = 0; e < 8; e++) {
      int m = kmap(g, e);
      float a = 0.f, c = 0.f;
      if (m < H) {
        float mu = accload(acc + m) * invN;
        float var = accload(acc + H + m) * invN - mu * mu;
        a = g0[m] * rsqrtf(var + EPS);
        c = be0[m] - a * mu;
      }
      aK[e] = a; cK[e] = c;
    }
    raw8(b1s, g, b1v);
    half8 A0 = buildA(W1s, H, H, 0, 0, g), A1 = buildA(W1s, H, H, 16, 0, g);
#pragma unroll
    for (int e = 0; e < 8; e++) { s[e] = 0.f; q[e] = 0.f; }
    half8 cur = bufT[fb];
#pragma unroll 1
    for (int i = 0; i < TPW; i++) {
      int ni = (i + 1 < TPW) ? (i + 1) : i;
      half8 nxt = bufT[fb + (size_t)ni * 64];
      half8 hb;
#pragma unroll
      for (int e = 0; e < 8; e++) hb[e] = (_Float16)(aK[e] * (float)cur[e] + cK[e]);
      bufT[fb + (size_t)i * 64] = hb;
      f32x4 c0 = {0.f, 0.f, 0.f, 0.f}, c1 = {0.f, 0.f, 0.f, 0.f};
      c0 = MFMA(A0, hb, c0);
      c1 = MFMA(A1, hb, c1);
#pragma unroll
      for (int e = 0; e < 8; e++) {
        float z = ((e < 4) ? c0[e & 3] : c1[e & 3]) + b1v[e];
        s[e] += z; q[e] += z * z;
      }
      cur = nxt;
    }
    commit_stats(s, q, red, acc + 44);
  }
  gridbar(bars + 1);

  // ================= 16 residual blocks =================
  float bo0 = bo[0];
#pragma unroll 1
  for (int k = 0; k < 16; k++) {
    const float* W1 = W1s + k * HH;
    const float* W2 = W2s + k * HH;

    // ---- P2: t = leaky(a1*(W1 h)+b1f) ; z2 = W2 t + b2 ; stats(z2)
    {
      float a1v[8], b1v[8], b2v[8];
      coeffs8(acc + (2 * k + 1) * 44, g1s + k * H, be1s + k * H, b1s + k * H,
              invN, g, a1v, b1v);
      raw8(b2s + k * H, g, b2v);
      half8 A10 = buildA(W1, H, H, 0, 0, g), A11 = buildA(W1, H, H, 16, 0, g);
      half8 A20 = buildA(W2, H, H, 0, 0, g), A21 = buildA(W2, H, H, 16, 0, g);
#pragma unroll
      for (int e = 0; e < 8; e++) { s[e] = 0.f; q[e] = 0.f; }
      half8 cur = bufT[fb];
#pragma unroll 1
      for (int i = 0; i < TPW; i++) {
        int ni = (i + 1 < TPW) ? (i + 1) : i;
        half8 nxt = bufT[fb + (size_t)ni * 64];
        f32x4 c0 = {0.f, 0.f, 0.f, 0.f}, c1 = {0.f, 0.f, 0.f, 0.f};
        c0 = MFMA(A10, cur, c0);
        c1 = MFMA(A11, cur, c1);
        half8 tb;
#pragma unroll
        for (int e = 0; e < 8; e++) {
          float c = (e < 4) ? c0[e & 3] : c1[e & 3];
          tb[e] = (_Float16)leakyf(a1v[e] * c + b1v[e]);
        }
        f32x4 d0 = {0.f, 0.f, 0.f, 0.f}, d1 = {0.f, 0.f, 0.f, 0.f};
        d0 = MFMA(A20, tb, d0);
        d1 = MFMA(A21, tb, d1);
#pragma unroll
        for (int e = 0; e < 8; e++) {
          float z = ((e < 4) ? d0[e & 3] : d1[e & 3]) + b2v[e];
          s[e] += z; q[e] += z * z;
        }
        cur = nxt;
      }
      commit_stats(s, q, red, acc + (2 * k + 2) * 44);
    }
    gridbar(bars + 2 + 2 * k);

    // ---- P3: h' = leaky(h + a2*(W2 t)+b2f) ; store ; next z1 stats / final out
    {
      float a1v[8], b1v[8], a2v[8], b2v[8], auxv[8];
      coeffs8(acc + (2 * k + 1) * 44, g1s + k * H, be1s + k * H, b1s + k * H,
              invN, g, a1v, b1v);
      coeffs8(acc + (2 * k + 2) * 44, g2s + k * H, be2s + k * H, b2s + k * H,
              invN, g, a2v, b2v);
      half8 A10 = buildA(W1, H, H, 0, 0, g), A11 = buildA(W1, H, H, 16, 0, g);
      half8 A20 = buildA(W2, H, H, 0, 0, g), A21 = buildA(W2, H, H, 16, 0, g);
      half8 An0 = {}, An1 = {};
      if (k < 15) {
        An0 = buildA(W1s + (k + 1) * HH, H, H, 0, 0, g);
        An1 = buildA(W1s + (k + 1) * HH, H, H, 16, 0, g);
        raw8(b1s + (k + 1) * H, g, auxv);
      } else {
        raw8(Wo, g, auxv);
      }
#pragma unroll
      for (int e = 0; e < 8; e++) { s[e] = 0.f; q[e] = 0.f; }
      half8 cur = bufT[fb];
#pragma unroll 1
      for (int i = 0; i < TPW; i++) {
        int ni = (i + 1 < TPW) ? (i + 1) : i;
        half8 nxt = bufT[fb + (size_t)ni * 64];
        f32x4 c0 = {0.f, 0.f, 0.f, 0.f}, c1 = {0.f, 0.f, 0.f, 0.f};
        c0 = MFMA(A10, cur, c0);
        c1 = MFMA(A11, cur, c1);
        half8 tb;
#pragma unroll
        for (int e = 0; e < 8; e++) {
          float c = (e < 4) ? c0[e & 3] : c1[e & 3];
          tb[e] = (_Float16)leakyf(a1v[e] * c + b1v[e]);
        }
        f32x4 d0 = {0.f, 0.f, 0.f, 0.f}, d1 = {0.f, 0.f, 0.f, 0.f};
        d0 = MFMA(A20, tb, d0);
        d1 = MFMA(A21, tb, d1);
        float hn[8];
        half8 nb;
#pragma unroll
        for (int e = 0; e < 8; e++) {
          float d = (e < 4) ? d0[e & 3] : d1[e & 3];
          hn[e] = leakyf((float)cur[e] + a2v[e] * d + b2v[e]);
          nb[e] = (_Float16)hn[e];
        }
        if (k < 15) {
          bufT[fb + (size_t)i * 64] = nb;
          f32x4 e0 = {0.f, 0.f, 0.f, 0.f}, e1 = {0.f, 0.f, 0.f, 0.f};
          e0 = MFMA(An0, nb, e0);
          e1 = MFMA(An1, nb, e1);
#pragma unroll
          for (int e = 0; e < 8; e++) {
            float z = ((e < 4) ? e0[e & 3] : e1[e & 3]) + auxv[e];
            s[e] += z; q[e] += z * z;
          }
        } else {
          float part = 0.f;
#pragma unroll
          for (int e = 0; e < 8; e++) part += auxv[e] * hn[e];
          part += __shfl_xor(part, 16);
          part += __shfl_xor(part, 32);
          if (lane < 16) out[(size_t)(tbase + i) * 16 + n] = part + bo0;
        }
        cur = nxt;
      }
      if (k < 15) {
        commit_stats(s, q, red, acc + (2 * k + 3) * 44);
        gridbar(bars + 3 + 2 * k);
      }
    }
  }
}

extern "C" void kernel_launch(void* const* d_in, const int* in_sizes, int n_in,
                              void* d_out, int out_size, void* d_ws, size_t ws_size,
                              hipStream_t stream) {
  const float* x    = (const float*)d_in[0];
  const float* Wp   = (const float*)d_in[1];
  const float* bp   = (const float*)d_in[2];
  const float* g0   = (const float*)d_in[3];
  const float* be0  = (const float*)d_in[4];
  const float* W1s  = (const float*)d_in[5];
  const float* b1s  = (const float*)d_in[6];
  const float* g1s  = (const float*)d_in[7];
  const float* be1s = (const float*)d_in[8];
  const float* W2s  = (const float*)d_in[9];
  const float* b2s  = (const float*)d_in[10];
  const float* g2s  = (const float*)d_in[11];
  const float* be2s = (const float*)d_in[12];
  const float* Wo   = (const float*)d_in[13];
  const float* bo   = (const float*)d_in[14];

  int N = in_sizes[0] / 64;  // 1048576
  int ntiles = N / 16;       // 65536
  float invN = 1.0f / (float)N;

  half8* bufT = (half8*)d_ws;                          // 64 MB f16 fragment buffer
  float* acc  = (float*)(bufT + (size_t)ntiles * 64);  // 33 stages x 44 floats
  int*   bars = (int*)(acc + 33 * 44);                 // 33 phase counters

  hipMemsetAsync(acc, 0, 33 * 44 * sizeof(float) + 64 * sizeof(int), stream);

  fused_kernel<<<dim3(NBLK), dim3(NT), 0, stream>>>(
      x, Wp, bp, g0, be0, W1s, b1s, g1s, be1s, W2s, b2s, g2s, be2s, Wo, bo,
      bufT, acc, bars, (float*)d_out, invN);
}

// Round 12
// 2676.833 us; speedup vs baseline: 5.2044x; 5.2044x over previous
//
#include <hip/hip_runtime.h>

#define H 22
#define HH 484
#define EPS 1e-5f
#define SLOPE 0.01f
#define NT 256
#define NBLK 512
#define WPB 4
#define NWAVES (NBLK * WPB)  // 2048 waves
#define TPW 32               // 65536 tiles / 2048 waves

typedef __attribute__((ext_vector_type(8))) _Float16 half8;
typedef __attribute__((ext_vector_type(4))) float f32x4;

#define MFMA(A, B, C) __builtin_amdgcn_mfma_f32_16x16x32_f16(A, B, C, 0, 0, 0)

__device__ __forceinline__ float leakyf(float u) { return u > 0.f ? u : SLOPE * u; }

// k/m map used consistently for all operands; C-frag m == B-elem k per lane,
// so chained matmuls repack in-lane (round-8 derivation, validated absmax 0.125).
__device__ __forceinline__ int kmap(int g, int e) {
  return ((e >> 2) << 4) + (g << 2) + (e & 3);
}

__device__ __forceinline__ half8 buildA(const float* __restrict__ W, int rows, int cols,
                                        int mbase, int kbase, int g) {
  int m = mbase + ((int)threadIdx.x & 15);
  half8 a;
#pragma unroll
  for (int e = 0; e < 8; e++) {
    int k = kbase + kmap(g, e);
    float v = (m < rows && k < cols) ? W[m * cols + k] : 0.f;
    a[e] = (_Float16)v;
  }
  return a;
}

__device__ __forceinline__ float accload(const float* p) {
  return __hip_atomic_load(p, __ATOMIC_ACQUIRE, __HIP_MEMORY_SCOPE_AGENT);
}

// ---- per-BLOCK staging into LDS (44 atomic loads/block/phase, like round 8) ----
// BN coeffs, bias-folded: cA[m]=a, cB[m]=a*b+be-a*mu ; zero-padded to 32
__device__ __forceinline__ void stage_bn(const float* __restrict__ accSt,
                                         const float* __restrict__ gg,
                                         const float* __restrict__ be,
                                         const float* __restrict__ b,
                                         float invN, float* cA, float* cB) {
  int tid = threadIdx.x;
  if (tid < 32) {
    float a = 0.f, bf = 0.f;
    if (tid < H) {
      float mu = accload(accSt + tid) * invN;
      float var = accload(accSt + H + tid) * invN - mu * mu;
      a = gg[tid] * rsqrtf(var + EPS);
      bf = a * b[tid] + be[tid] - a * mu;
    }
    cA[tid] = a; cB[tid] = bf;
  }
}
// BN coeffs, unfolded (for bn0): cA[m]=a, cB[m]=be-a*mu
__device__ __forceinline__ void stage_bn_nf(const float* __restrict__ accSt,
                                            const float* __restrict__ gg,
                                            const float* __restrict__ be,
                                            float invN, float* cA, float* cB) {
  int tid = threadIdx.x;
  if (tid < 32) {
    float a = 0.f, c = 0.f;
    if (tid < H) {
      float mu = accload(accSt + tid) * invN;
      float var = accload(accSt + H + tid) * invN - mu * mu;
      a = gg[tid] * rsqrtf(var + EPS);
      c = be[tid] - a * mu;
    }
    cA[tid] = a; cB[tid] = c;
  }
}
__device__ __forceinline__ void stage_raw(const float* __restrict__ p, float* c) {
  int tid = threadIdx.x;
  if (tid < 32) c[tid] = (tid < H) ? p[tid] : 0.f;
}
__device__ __forceinline__ void gather8(const float* c, int g, float* v) {
#pragma unroll
  for (int e = 0; e < 8; e++) v[e] = c[kmap(g, e)];
}

__device__ __forceinline__ void commit_stats(float* s, float* q,
                                             float red[WPB][2 * H],
                                             float* __restrict__ accOut) {
  int lane = (int)threadIdx.x & 63, w = (int)threadIdx.x >> 6, g = lane >> 4;
#pragma unroll
  for (int r = 0; r < 8; r++) {
#pragma unroll
    for (int off = 1; off < 16; off <<= 1) {
      s[r] += __shfl_xor(s[r], off);
      q[r] += __shfl_xor(q[r], off);
    }
  }
  if ((lane & 15) == 0) {
#pragma unroll
    for (int r = 0; r < 8; r++) {
      int m = kmap(g, r);
      if (m < H) { red[w][m] = s[r]; red[w][H + m] = q[r]; }
    }
  }
  __syncthreads();
  if ((int)threadIdx.x < 2 * H) {
    float v = red[0][threadIdx.x] + red[1][threadIdx.x] +
              red[2][threadIdx.x] + red[3][threadIdx.x];
    atomicAdd(&accOut[threadIdx.x], v);
  }
  __syncthreads();
}

// device-wide barrier; all NBLK blocks co-resident (2 blocks/CU by waves_per_eu(2,2))
__device__ __forceinline__ void gridbar(int* bar) {
  __syncthreads();
  if (threadIdx.x == 0) {
    __hip_atomic_fetch_add(bar, 1, __ATOMIC_ACQ_REL, __HIP_MEMORY_SCOPE_AGENT);
    while (__hip_atomic_load(bar, __ATOMIC_ACQUIRE, __HIP_MEMORY_SCOPE_AGENT) < NBLK)
      __builtin_amdgcn_s_sleep(2);
  }
  __syncthreads();
}

__global__ void __launch_bounds__(NT) __attribute__((amdgpu_waves_per_eu(2, 2)))
fused_kernel(
    const float* __restrict__ x, const float* __restrict__ Wp,
    const float* __restrict__ bp, const float* __restrict__ g0,
    const float* __restrict__ be0,
    const float* __restrict__ W1s, const float* __restrict__ b1s,
    const float* __restrict__ g1s, const float* __restrict__ be1s,
    const float* __restrict__ W2s, const float* __restrict__ b2s,
    const float* __restrict__ g2s, const float* __restrict__ be2s,
    const float* __restrict__ Wo, const float* __restrict__ bo,
    half8* __restrict__ bufT, float* __restrict__ acc,
    int* __restrict__ bars, float* __restrict__ out, float invN) {
  __shared__ float red[WPB][2 * H];
  __shared__ float sc0[32], sc1[32], sc2[32], sc3[32], sc4[32];
  int tid = threadIdx.x;
  int lane = tid & 63, g = lane >> 4, n = lane & 15;
  int wid = blockIdx.x * WPB + (tid >> 6);
  int tbase = wid * TPW;
  size_t fb = (size_t)tbase * 64 + g * 16 + n;

  float s[8], q[8];

  // ================= Phase 0: proj  z0 = Wp@x + bp =================
  {
    stage_raw(bp, sc0);
    __syncthreads();
    half8 A00 = buildA(Wp, H, 64, 0, 0, g);
    half8 A01 = buildA(Wp, H, 64, 0, 32, g);
    half8 A10 = buildA(Wp, H, 64, 16, 0, g);
    half8 A11 = buildA(Wp, H, 64, 16, 32, g);
    float bpv[8]; gather8(sc0, g, bpv);
#pragma unroll
    for (int e = 0; e < 8; e++) { s[e] = 0.f; q[e] = 0.f; }
    const float4* x4 = (const float4*)x;
#pragma unroll 1
    for (int i = 0; i < TPW; i++) {
      size_t row = (size_t)(tbase + i) * 16 + n;
      float4 L0 = x4[row * 16 + g];
      float4 L1 = x4[row * 16 + 4 + g];
      float4 L2 = x4[row * 16 + 8 + g];
      float4 L3 = x4[row * 16 + 12 + g];
      half8 B0, B1;
      B0[0] = (_Float16)L0.x; B0[1] = (_Float16)L0.y; B0[2] = (_Float16)L0.z; B0[3] = (_Float16)L0.w;
      B0[4] = (_Float16)L1.x; B0[5] = (_Float16)L1.y; B0[6] = (_Float16)L1.z; B0[7] = (_Float16)L1.w;
      B1[0] = (_Float16)L2.x; B1[1] = (_Float16)L2.y; B1[2] = (_Float16)L2.z; B1[3] = (_Float16)L2.w;
      B1[4] = (_Float16)L3.x; B1[5] = (_Float16)L3.y; B1[6] = (_Float16)L3.z; B1[7] = (_Float16)L3.w;
      f32x4 c0 = {0.f, 0.f, 0.f, 0.f}, c1 = {0.f, 0.f, 0.f, 0.f};
      c0 = MFMA(A00, B0, c0); c0 = MFMA(A01, B1, c0);
      c1 = MFMA(A10, B0, c1); c1 = MFMA(A11, B1, c1);
      half8 zb;
#pragma unroll
      for (int e = 0; e < 8; e++) {
        float z = ((e < 4) ? c0[e & 3] : c1[e & 3]) + bpv[e];
        s[e] += z; q[e] += z * z;
        zb[e] = (_Float16)z;
      }
      bufT[fb + (size_t)i * 64] = zb;
    }
    commit_stats(s, q, red, acc + 0);
  }
  gridbar(bars + 0);

  // ================= Phase 1: bn0 in place + stats z1_0 =================
  {
    stage_bn_nf(acc + 0, g0, be0, invN, sc0, sc1);
    stage_raw(b1s, sc2);
    __syncthreads();
    float aK[8], cK[8], b1v[8];
    gather8(sc0, g, aK); gather8(sc1, g, cK); gather8(sc2, g, b1v);
    half8 A0 = buildA(W1s, H, H, 0, 0, g), A1 = buildA(W1s, H, H, 16, 0, g);
#pragma unroll
    for (int e = 0; e < 8; e++) { s[e] = 0.f; q[e] = 0.f; }
#pragma unroll 1
    for (int i = 0; i < TPW; i++) {
      half8 cur = bufT[fb + (size_t)i * 64];
      half8 hb;
#pragma unroll
      for (int e = 0; e < 8; e++) hb[e] = (_Float16)(aK[e] * (float)cur[e] + cK[e]);
      bufT[fb + (size_t)i * 64] = hb;
      f32x4 c0 = {0.f, 0.f, 0.f, 0.f}, c1 = {0.f, 0.f, 0.f, 0.f};
      c0 = MFMA(A0, hb, c0);
      c1 = MFMA(A1, hb, c1);
#pragma unroll
      for (int e = 0; e < 8; e++) {
        float z = ((e < 4) ? c0[e & 3] : c1[e & 3]) + b1v[e];
        s[e] += z; q[e] += z * z;
      }
    }
    commit_stats(s, q, red, acc + 44);
  }
  gridbar(bars + 1);

  // ================= 16 residual blocks =================
  float bo0 = bo[0];
#pragma unroll 1
  for (int k = 0; k < 16; k++) {
    const float* W1 = W1s + k * HH;
    const float* W2 = W2s + k * HH;

    // ---- P2: t = leaky(a1*(W1 h)+b1f) ; z2 = W2 t + b2 ; stats(z2)
    {
      stage_bn(acc + (2 * k + 1) * 44, g1s + k * H, be1s + k * H, b1s + k * H,
               invN, sc0, sc1);
      stage_raw(b2s + k * H, sc2);
      __syncthreads();
      float a1v[8], b1v[8], b2v[8];
      gather8(sc0, g, a1v); gather8(sc1, g, b1v); gather8(sc2, g, b2v);
      half8 A10 = buildA(W1, H, H, 0, 0, g), A11 = buildA(W1, H, H, 16, 0, g);
      half8 A20 = buildA(W2, H, H, 0, 0, g), A21 = buildA(W2, H, H, 16, 0, g);
#pragma unroll
      for (int e = 0; e < 8; e++) { s[e] = 0.f; q[e] = 0.f; }
#pragma unroll 1
      for (int i = 0; i < TPW; i++) {
        half8 cur = bufT[fb + (size_t)i * 64];
        f32x4 c0 = {0.f, 0.f, 0.f, 0.f}, c1 = {0.f, 0.f, 0.f, 0.f};
        c0 = MFMA(A10, cur, c0);
        c1 = MFMA(A11, cur, c1);
        half8 tb;
#pragma unroll
        for (int e = 0; e < 8; e++) {
          float c = (e < 4) ? c0[e & 3] : c1[e & 3];
          tb[e] = (_Float16)leakyf(a1v[e] * c + b1v[e]);
        }
        f32x4 d0 = {0.f, 0.f, 0.f, 0.f}, d1 = {0.f, 0.f, 0.f, 0.f};
        d0 = MFMA(A20, tb, d0);
        d1 = MFMA(A21, tb, d1);
#pragma unroll
        for (int e = 0; e < 8; e++) {
          float z = ((e < 4) ? d0[e & 3] : d1[e & 3]) + b2v[e];
          s[e] += z; q[e] += z * z;
        }
      }
      commit_stats(s, q, red, acc + (2 * k + 2) * 44);
    }
    gridbar(bars + 2 + 2 * k);

    // ---- P3: h' = leaky(h + a2*(W2 t)+b2f) ; store ; next z1 stats / final out
    {
      stage_bn(acc + (2 * k + 1) * 44, g1s + k * H, be1s + k * H, b1s + k * H,
               invN, sc0, sc1);
      stage_bn(acc + (2 * k + 2) * 44, g2s + k * H, be2s + k * H, b2s + k * H,
               invN, sc2, sc3);
      stage_raw(k < 15 ? b1s + (k + 1) * H : Wo, sc4);
      __syncthreads();
      float a1v[8], b1v[8], a2v[8], b2v[8], auxv[8];
      gather8(sc0, g, a1v); gather8(sc1, g, b1v);
      gather8(sc2, g, a2v); gather8(sc3, g, b2v); gather8(sc4, g, auxv);
      half8 A10 = buildA(W1, H, H, 0, 0, g), A11 = buildA(W1, H, H, 16, 0, g);
      half8 A20 = buildA(W2, H, H, 0, 0, g), A21 = buildA(W2, H, H, 16, 0, g);
      half8 An0 = {}, An1 = {};
      if (k < 15) {
        An0 = buildA(W1s + (k + 1) * HH, H, H, 0, 0, g);
        An1 = buildA(W1s + (k + 1) * HH, H, H, 16, 0, g);
      }
#pragma unroll
      for (int e = 0; e < 8; e++) { s[e] = 0.f; q[e] = 0.f; }
#pragma unroll 1
      for (int i = 0; i < TPW; i++) {
        half8 cur = bufT[fb + (size_t)i * 64];
        f32x4 c0 = {0.f, 0.f, 0.f, 0.f}, c1 = {0.f, 0.f, 0.f, 0.f};
        c0 = MFMA(A10, cur, c0);
        c1 = MFMA(A11, cur, c1);
        half8 tb;
#pragma unroll
        for (int e = 0; e < 8; e++) {
          float c = (e < 4) ? c0[e & 3] : c1[e & 3];
          tb[e] = (_Float16)leakyf(a1v[e] * c + b1v[e]);
        }
        f32x4 d0 = {0.f, 0.f, 0.f, 0.f}, d1 = {0.f, 0.f, 0.f, 0.f};
        d0 = MFMA(A20, tb, d0);
        d1 = MFMA(A21, tb, d1);
        float hn[8];
        half8 nb;
#pragma unroll
        for (int e = 0; e < 8; e++) {
          float d = (e < 4) ? d0[e & 3] : d1[e & 3];
          hn[e] = leakyf((float)cur[e] + a2v[e] * d + b2v[e]);
          nb[e] = (_Float16)hn[e];
        }
        if (k < 15) {
          bufT[fb + (size_t)i * 64] = nb;
          f32x4 e0 = {0.f, 0.f, 0.f, 0.f}, e1 = {0.f, 0.f, 0.f, 0.f};
          e0 = MFMA(An0, nb, e0);
          e1 = MFMA(An1, nb, e1);
#pragma unroll
          for (int e = 0; e < 8; e++) {
            float z = ((e < 4) ? e0[e & 3] : e1[e & 3]) + auxv[e];
            s[e] += z; q[e] += z * z;
          }
        } else {
          float part = 0.f;
#pragma unroll
          for (int e = 0; e < 8; e++) part += auxv[e] * hn[e];
          part += __shfl_xor(part, 16);
          part += __shfl_xor(part, 32);
          if (lane < 16) out[(size_t)(tbase + i) * 16 + n] = part + bo0;
        }
      }
      if (k < 15) {
        commit_stats(s, q, red, acc + (2 * k + 3) * 44);
        gridbar(bars + 3 + 2 * k);
      }
    }
  }
}

extern "C" void kernel_launch(void* const* d_in, const int* in_sizes, int n_in,
                              void* d_out, int out_size, void* d_ws, size_t ws_size,
                              hipStream_t stream) {
  const float* x    = (const float*)d_in[0];
  const float* Wp   = (const float*)d_in[1];
  const float* bp   = (const float*)d_in[2];
  const float* g0   = (const float*)d_in[3];
  const float* be0  = (const float*)d_in[4];
  const float* W1s  = (const float*)d_in[5];
  const float* b1s  = (const float*)d_in[6];
  const float* g1s  = (const float*)d_in[7];
  const float* be1s = (const float*)d_in[8];
  const float* W2s  = (const float*)d_in[9];
  const float* b2s  = (const float*)d_in[10];
  const float* g2s  = (const float*)d_in[11];
  const float* be2s = (const float*)d_in[12];
  const float* Wo   = (const float*)d_in[13];
  const float* bo   = (const float*)d_in[14];

  int N = in_sizes[0] / 64;  // 1048576
  int ntiles = N / 16;       // 65536
  float invN = 1.0f / (float)N;

  half8* bufT = (half8*)d_ws;                          // 64 MB f16 fragment buffer
  float* acc  = (float*)(bufT + (size_t)ntiles * 64);  // 33 stages x 44 floats
  int*   bars = (int*)(acc + 33 * 44);                 // 33 phase counters

  hipMemsetAsync(acc, 0, 33 * 44 * sizeof(float) + 64 * sizeof(int), stream);

  fused_kernel<<<dim3(NBLK), dim3(NT), 0, stream>>>(
      x, Wp, bp, g0, be0, W1s, b1s, g1s, be1s, W2s, b2s, g2s, be2s, Wo, bo,
      bufT, acc, bars, (float*)d_out, invN);
}